// Round 3
// baseline (972.678 us; speedup 1.0000x reference)
//
#include <hip/hip_runtime.h>
#include <hip/hip_bf16.h>

// GraphRNN, fp32 I/O (reference dtypes are float32).
// beta = (seq @ E) / rowsum(graph); agg = graph^T @ beta (per batch);
// Xpre = agg @ Wx + b; then 1024-step scan h = tanh(Xpre_m + h @ Wh).
// MFMA path: fp32 operands split into bf16 hi+lo (rel err ~2^-18).
//
// R14: 4-wave scan. R13 (8 waves/WG, quad0-only epilogue) measured
// 1590cy/step; accounting: 64 ds_read_b128/step on one CU's LDS pipe
// (~12cy each = ~768cy) dominated — broadcast kills conflicts, not issue
// slots. Per-SIMD MFMA issue is constant (256 MFMA total / 4 SIMDs ~310cy)
// regardless of wave count, so: 4 waves x 64 cols -> 32 reads (~384cy,
// overlaps MFMA on separate pipe). Epilogue: A-rows 2..15 are bit-exact
// dups of rows 0/1, so EVERY quad's C regs[0,1] hold valid (hi,lo);
// quad q consumes n-tile q via static selects -> 1 tanh/lane, lane-linear
// h-writes (col = colbase+lane, conflict-free), coalesced out-stores.
// Per-accumulator MFMA order and recombine order unchanged -> bit-identical.

typedef unsigned short u16;
typedef unsigned int u32;
typedef __bf16 bf16_t;
typedef __bf16 bf16x8 __attribute__((ext_vector_type(8)));
typedef float f32x4 __attribute__((ext_vector_type(4)));
typedef unsigned short u16x8 __attribute__((ext_vector_type(8)));
typedef unsigned short u16x4 __attribute__((ext_vector_type(4)));

#define LDS_P 72   // LDS pitch (u16) for 64-wide tiles (GEMM kernels)
#define HP_B  288  // h LDS row pitch (u16): row1 starts at dword 144 ->
                   // banks 16.. for row1 vs 0..15 for row0 quad chunks

struct HiLo { u16 hi, lo; };

__device__ __forceinline__ u16 f2bf(float f) {
  bf16_t h = (bf16_t)f;  // RNE
  return __builtin_bit_cast(u16, h);
}
__device__ __forceinline__ HiLo splitf(float v) {
  bf16_t h = (bf16_t)v;
  HiLo r;
  r.hi = __builtin_bit_cast(u16, h);
  r.lo = f2bf(v - (float)h);
  return r;
}
__device__ __forceinline__ float tanh_fast(float x) {
  float ax = fabsf(x);
  float e  = __expf(-2.0f * ax);
  float t  = __fdividef(1.0f - e, 1.0f + e);
  return copysignf(t, x);
}
// Barrier with LDS-only visibility (drains lgkmcnt, not vmcnt).
__device__ __forceinline__ void sync_lds_only() {
  __asm__ volatile("s_waitcnt lgkmcnt(0)\ns_barrier" ::: "memory");
}

// ---------------- K0: transpose + hi/lo split of E, Wx, Wh ------------------
__global__ void transpose_split3(const float* __restrict__ s0, u16* __restrict__ h0, u16* __restrict__ l0,
                                 const float* __restrict__ s1, u16* __restrict__ h1, u16* __restrict__ l1,
                                 const float* __restrict__ s2, u16* __restrict__ h2o, u16* __restrict__ l2o) {
  const int u = blockIdx.x, d = threadIdx.x;
  const float* s; u16 *dh, *dl;
  if (blockIdx.y == 0)      { s = s0; dh = h0;  dl = l0; }
  else if (blockIdx.y == 1) { s = s1; dh = h1;  dl = l1; }
  else                      { s = s2; dh = h2o; dl = l2o; }
  HiLo r = splitf(s[d * 256 + u]);
  dh[u * 256 + d] = r.hi;
  dl[u * 256 + d] = r.lo;
}

// ---------------- K1: rnorm[b,l] = 1 / max(sum_m graph[b,l,m], 1e-7) --------
__global__ void rowsum_norm(const float* __restrict__ graph, float* __restrict__ rnorm) {
  const int wave = threadIdx.x >> 6, lane = threadIdx.x & 63;
  const int row = blockIdx.x * 4 + wave;  // 0..8191
  const float* p = graph + (size_t)row * 1024 + lane * 16;
  float s = 0.f;
#pragma unroll
  for (int c = 0; c < 4; c++) {
    f32x4 v = *(const f32x4*)(p + c * 4);
#pragma unroll
    for (int j = 0; j < 4; j++) s += v[j];
  }
#pragma unroll
  for (int off = 32; off > 0; off >>= 1) s += __shfl_xor(s, off);
  if (lane == 0) rnorm[row] = 1.0f / fmaxf(s, 1e-7f);
}

// ---------------- K2: betaT[b][u][l] hi/lo = (seq@E)[b,l,u] * rnorm[b,l] ----
__global__ __launch_bounds__(256, 2) void gemm_beta(const float* __restrict__ seq,
                                                    const u16* __restrict__ Eth,
                                                    const u16* __restrict__ Etl,
                                                    const float* __restrict__ rnorm,
                                                    u16* __restrict__ betaTh,
                                                    u16* __restrict__ betaTl) {
  __shared__ u16 Ah[64 * LDS_P], Al[64 * LDS_P];
  __shared__ u16 Bh[64 * LDS_P], Bl[64 * LDS_P];
  const int t = threadIdx.x;
  const int wave = t >> 6, lane = t & 63, quad = lane >> 4, l16 = lane & 15;
  const int r0 = blockIdx.x * 64, n0 = blockIdx.y * 64;
  f32x4 acc[4];
#pragma unroll
  for (int i = 0; i < 4; i++) acc[i] = (f32x4){0.f, 0.f, 0.f, 0.f};

  for (int kb = 0; kb < 256; kb += 64) {
#pragma unroll
    for (int cc = 0; cc < 4; cc++) {
      int c = t + cc * 256;
      int r = c >> 4, c4 = c & 15;
      f32x4 v = *(const f32x4*)(seq + (size_t)(r0 + r) * 256 + kb + c4 * 4);
      u16x4 hi, lo;
#pragma unroll
      for (int j = 0; j < 4; j++) {
        HiLo s = splitf(v[j]);
        hi[j] = s.hi; lo[j] = s.lo;
      }
      *(u16x4*)(Ah + r * LDS_P + c4 * 4) = hi;
      *(u16x4*)(Al + r * LDS_P + c4 * 4) = lo;
    }
#pragma unroll
    for (int cc = 0; cc < 2; cc++) {
      int c = t + cc * 256;
      int r = c >> 3, c8 = c & 7;
      *(u16x8*)(Bh + r * LDS_P + c8 * 8) =
          *(const u16x8*)(Eth + (size_t)(n0 + r) * 256 + kb + c8 * 8);
      *(u16x8*)(Bl + r * LDS_P + c8 * 8) =
          *(const u16x8*)(Etl + (size_t)(n0 + r) * 256 + kb + c8 * 8);
    }
    __syncthreads();
#pragma unroll
    for (int kk = 0; kk < 64; kk += 32) {
      bf16x8 ah = __builtin_bit_cast(bf16x8, *(const u16x8*)(Ah + (wave * 16 + l16) * LDS_P + kk + quad * 8));
      bf16x8 al = __builtin_bit_cast(bf16x8, *(const u16x8*)(Al + (wave * 16 + l16) * LDS_P + kk + quad * 8));
#pragma unroll
      for (int tN = 0; tN < 4; tN++) {
        bf16x8 bh = __builtin_bit_cast(bf16x8, *(const u16x8*)(Bh + (tN * 16 + l16) * LDS_P + kk + quad * 8));
        bf16x8 bl = __builtin_bit_cast(bf16x8, *(const u16x8*)(Bl + (tN * 16 + l16) * LDS_P + kk + quad * 8));
        acc[tN] = __builtin_amdgcn_mfma_f32_16x16x32_bf16(ah, bh, acc[tN], 0, 0, 0);
        acc[tN] = __builtin_amdgcn_mfma_f32_16x16x32_bf16(ah, bl, acc[tN], 0, 0, 0);
        acc[tN] = __builtin_amdgcn_mfma_f32_16x16x32_bf16(al, bh, acc[tN], 0, 0, 0);
      }
    }
    __syncthreads();
  }
  const int rbase = r0 + wave * 16 + quad * 4;  // b*1024 + l, 4 consecutive l
  float rn[4];
#pragma unroll
  for (int i = 0; i < 4; i++) rn[i] = rnorm[rbase + i];
  const int bI = rbase >> 10, lI = rbase & 1023;
#pragma unroll
  for (int tN = 0; tN < 4; tN++) {
    int u = n0 + tN * 16 + l16;
    u16x4 hv, lv;
#pragma unroll
    for (int i = 0; i < 4; i++) {
      HiLo s = splitf(acc[tN][i] * rn[i]);
      hv[i] = s.hi; lv[i] = s.lo;
    }
    size_t off = ((size_t)bI << 18) + (size_t)u * 1024 + lI;
    *(u16x4*)(betaTh + off) = hv;
    *(u16x4*)(betaTl + off) = lv;
  }
}

// ---------------- K3: agg[b][m][u] = sum_l graph[b][l][m] * beta[b][l][u] ---
__global__ __launch_bounds__(256, 2) void gemm_agg(const float* __restrict__ graph,
                                                   const u16* __restrict__ betaTh,
                                                   const u16* __restrict__ betaTl,
                                                   float* __restrict__ agg) {
  __shared__ u16 Ah[64 * LDS_P], Al[64 * LDS_P];
  __shared__ u16 Bh[64 * LDS_P], Bl[64 * LDS_P];
  const int t = threadIdx.x;
  const int wave = t >> 6, lane = t & 63, quad = lane >> 4, l16 = lane & 15;
  const int m0 = blockIdx.x * 64, n0 = blockIdx.y * 64, b = blockIdx.z;
  const float* g = graph + (size_t)b * (1024 * 1024);
  const size_t bt = (size_t)b << 18;
  f32x4 acc[4];
#pragma unroll
  for (int i = 0; i < 4; i++) acc[i] = (f32x4){0.f, 0.f, 0.f, 0.f};

  for (int kb = 0; kb < 1024; kb += 64) {
#pragma unroll
    for (int cc = 0; cc < 4; cc++) {
      int c = t + cc * 256;
      int r = c >> 4, c4 = c & 15;  // r = l_local, c4 = m-chunk of 4
      f32x4 v = *(const f32x4*)(g + (size_t)(kb + r) * 1024 + m0 + c4 * 4);
#pragma unroll
      for (int j = 0; j < 4; j++) {
        HiLo s = splitf(v[j]);
        Ah[(c4 * 4 + j) * LDS_P + r] = s.hi;  // A[m][l] = graph[l][m]
        Al[(c4 * 4 + j) * LDS_P + r] = s.lo;
      }
    }
#pragma unroll
    for (int cc = 0; cc < 2; cc++) {
      int c = t + cc * 256;
      int r = c >> 3, c8 = c & 7;
      *(u16x8*)(Bh + r * LDS_P + c8 * 8) =
          *(const u16x8*)(betaTh + bt + (size_t)(n0 + r) * 1024 + kb + c8 * 8);
      *(u16x8*)(Bl + r * LDS_P + c8 * 8) =
          *(const u16x8*)(betaTl + bt + (size_t)(n0 + r) * 1024 + kb + c8 * 8);
    }
    __syncthreads();
#pragma unroll
    for (int kk = 0; kk < 64; kk += 32) {
      bf16x8 ah = __builtin_bit_cast(bf16x8, *(const u16x8*)(Ah + (wave * 16 + l16) * LDS_P + kk + quad * 8));
      bf16x8 al = __builtin_bit_cast(bf16x8, *(const u16x8*)(Al + (wave * 16 + l16) * LDS_P + kk + quad * 8));
#pragma unroll
      for (int tN = 0; tN < 4; tN++) {
        bf16x8 bh = __builtin_bit_cast(bf16x8, *(const u16x8*)(Bh + (tN * 16 + l16) * LDS_P + kk + quad * 8));
        bf16x8 bl = __builtin_bit_cast(bf16x8, *(const u16x8*)(Bl + (tN * 16 + l16) * LDS_P + kk + quad * 8));
        acc[tN] = __builtin_amdgcn_mfma_f32_16x16x32_bf16(ah, bh, acc[tN], 0, 0, 0);
        acc[tN] = __builtin_amdgcn_mfma_f32_16x16x32_bf16(ah, bl, acc[tN], 0, 0, 0);
        acc[tN] = __builtin_amdgcn_mfma_f32_16x16x32_bf16(al, bh, acc[tN], 0, 0, 0);
      }
    }
    __syncthreads();
  }
  const int mbase = m0 + wave * 16 + quad * 4;
#pragma unroll
  for (int tN = 0; tN < 4; tN++) {
    int u = n0 + tN * 16 + l16;
#pragma unroll
    for (int i = 0; i < 4; i++)
      agg[((size_t)b * 1024 + mbase + i) * 256 + u] = acc[tN][i];
  }
}

// ---------------- K4: Xpre[m][b][u] = (agg @ Wx)[b,m,u] + bias[u] (fp32) ----
__global__ __launch_bounds__(256, 2) void gemm_xpre(const float* __restrict__ agg,
                                                    const u16* __restrict__ Wxth,
                                                    const u16* __restrict__ Wxtl,
                                                    const float* __restrict__ bias,
                                                    float* __restrict__ Xpre) {
  __shared__ u16 Ah[64 * LDS_P], Al[64 * LDS_P];
  __shared__ u16 Bh[64 * LDS_P], Bl[64 * LDS_P];
  const int t = threadIdx.x;
  const int wave = t >> 6, lane = t & 63, quad = lane >> 4, l16 = lane & 15;
  const int r0 = blockIdx.x * 64, n0 = blockIdx.y * 64;
  f32x4 acc[4];
#pragma unroll
  for (int i = 0; i < 4; i++) acc[i] = (f32x4){0.f, 0.f, 0.f, 0.f};

  for (int kb = 0; kb < 256; kb += 64) {
#pragma unroll
    for (int cc = 0; cc < 4; cc++) {
      int c = t + cc * 256;
      int r = c >> 4, c4 = c & 15;
      f32x4 v = *(const f32x4*)(agg + (size_t)(r0 + r) * 256 + kb + c4 * 4);
      u16x4 hi, lo;
#pragma unroll
      for (int j = 0; j < 4; j++) {
        HiLo s = splitf(v[j]);
        hi[j] = s.hi; lo[j] = s.lo;
      }
      *(u16x4*)(Ah + r * LDS_P + c4 * 4) = hi;
      *(u16x4*)(Al + r * LDS_P + c4 * 4) = lo;
    }
#pragma unroll
    for (int cc = 0; cc < 2; cc++) {
      int c = t + cc * 256;
      int r = c >> 3, c8 = c & 7;
      *(u16x8*)(Bh + r * LDS_P + c8 * 8) =
          *(const u16x8*)(Wxth + (size_t)(n0 + r) * 256 + kb + c8 * 8);
      *(u16x8*)(Bl + r * LDS_P + c8 * 8) =
          *(const u16x8*)(Wxtl + (size_t)(n0 + r) * 256 + kb + c8 * 8);
    }
    __syncthreads();
#pragma unroll
    for (int kk = 0; kk < 64; kk += 32) {
      bf16x8 ah = __builtin_bit_cast(bf16x8, *(const u16x8*)(Ah + (wave * 16 + l16) * LDS_P + kk + quad * 8));
      bf16x8 al = __builtin_bit_cast(bf16x8, *(const u16x8*)(Al + (wave * 16 + l16) * LDS_P + kk + quad * 8));
#pragma unroll
      for (int tN = 0; tN < 4; tN++) {
        bf16x8 bh = __builtin_bit_cast(bf16x8, *(const u16x8*)(Bh + (tN * 16 + l16) * LDS_P + kk + quad * 8));
        bf16x8 bl = __builtin_bit_cast(bf16x8, *(const u16x8*)(Bl + (tN * 16 + l16) * LDS_P + kk + quad * 8));
        acc[tN] = __builtin_amdgcn_mfma_f32_16x16x32_bf16(ah, bh, acc[tN], 0, 0, 0);
        acc[tN] = __builtin_amdgcn_mfma_f32_16x16x32_bf16(ah, bl, acc[tN], 0, 0, 0);
        acc[tN] = __builtin_amdgcn_mfma_f32_16x16x32_bf16(al, bh, acc[tN], 0, 0, 0);
      }
    }
    __syncthreads();
  }
  const int rbase = r0 + wave * 16 + quad * 4;  // b*1024 + m
  const int bI = rbase >> 10;
#pragma unroll
  for (int tN = 0; tN < 4; tN++) {
    int u = n0 + tN * 16 + l16;
    float bu = bias[u];
#pragma unroll
    for (int i = 0; i < 4; i++) {
      int mI = (rbase + i) & 1023;
      Xpre[((size_t)mI * 8 + bI) * 256 + u] = acc[tN][i] + bu;
    }
  }
}

// ---------------- K5: sequential scan, 8 WGs (1 batch each), 4 waves --------
// Wave w owns output cols [w*64, w*64+64) = 4 n-tiles. A-tile: 2 rows
// (h_hi, h_lo), read row clamped to l16&1 -> broadcast, conflict-free.
// 32 ds_read_b128/step total (half of R13's 64 — the LDS-pipe bottleneck).
// All C rows are bit-exact duplicates of rows 0/1, so every quad holds
// (hi,lo) in regs [0],[1]; quad q consumes n-tile q via static selects:
// col = colbase + quad*16 + l16 = colbase + lane -> lane-linear h-writes
// and coalesced out-stores, 1 tanh/lane. Bit-identical math to R13.
__global__ __launch_bounds__(256, 1) void rnn_scan(const u16* __restrict__ Whth,
                                                   const u16* __restrict__ Whtl,
                                                   const float* __restrict__ Xpre,
                                                   float* __restrict__ out) {
  __shared__ u16 h2[2][2 * HP_B];
  const int b = blockIdx.x;
  const int t = threadIdx.x;
  const int w = t >> 6, lane = t & 63, quad = lane >> 4, l16 = lane & 15;
  const int colbase = w * 64;
  const int cwl = colbase + lane;        // this lane's epilogue column

  // Preload Wh hi+lo fragments: 4 n-tiles x 8 k-blocks, hi+lo (~256 regs,
  // AGPR-backed on gfx950 unified file; launch_bounds(256,1) -> no spill).
  bf16x8 bwh[4][8], bwl[4][8];
#pragma unroll
  for (int tN = 0; tN < 4; tN++) {
    const u16* wph = Whth + (size_t)(colbase + tN * 16 + l16) * 256 + quad * 8;
    const u16* wpl = Whtl + (size_t)(colbase + tN * 16 + l16) * 256 + quad * 8;
#pragma unroll
    for (int kb = 0; kb < 8; kb++) {
      bwh[tN][kb] = __builtin_bit_cast(bf16x8, *(const u16x8*)(wph + kb * 32));
      bwl[tN][kb] = __builtin_bit_cast(bf16x8, *(const u16x8*)(wpl + kb * 32));
    }
  }
  for (int i = t; i < 2 * 2 * HP_B; i += 256) ((u16*)h2)[i] = 0;

  // c banks 0..3 hold the additive input for steps m4+0..m4+3 (lookahead 4).
  float cb[4];
#pragma unroll
  for (int k = 0; k < 4; k++) cb[k] = Xpre[(size_t)k * 2048 + b * 256 + cwl];
  // Running pointers (advance by constants; no per-step re-derivation).
  const float* ldp = Xpre + 4 * 2048 + b * 256 + cwl;
  float* outp = out + (size_t)b * 262144 + cwl;
  // Hoisted LDS bases. Read base: row clamped to l16&1 (broadcast dup rows).
  const u16* rb0 = &h2[0][(l16 & 1) * HP_B + quad * 8];
  const u16* rb1 = &h2[1][(l16 & 1) * HP_B + quad * 8];
  u16* wb0 = &h2[0][0];
  u16* wb1 = &h2[1][0];
  __syncthreads();

  for (int m4 = 0; m4 < 1024; m4 += 4) {
#pragma unroll
    for (int k = 0; k < 4; k++) {
      const int p = k & 1;                       // compile-time in unrolled body
      const u16* rb = p ? rb1 : rb0;
      u16* hw = p ? wb0 : wb1;                   // write the other buffer

      f32x4 aA[4], aB[4];
#pragma unroll
      for (int i = 0; i < 4; i++) { aA[i] = (f32x4){0.f,0.f,0.f,0.f}; aB[i] = (f32x4){0.f,0.f,0.f,0.f}; }
#pragma unroll
      for (int kb = 0; kb < 4; kb++) {
        bf16x8 afA = __builtin_bit_cast(bf16x8, *(const u16x8*)(rb + kb * 32));
        bf16x8 afB = __builtin_bit_cast(bf16x8, *(const u16x8*)(rb + (kb + 4) * 32));
#pragma unroll
        for (int tN = 0; tN < 4; tN++) {
          aA[tN] = __builtin_amdgcn_mfma_f32_16x16x32_bf16(afA, bwh[tN][kb], aA[tN], 0, 0, 0);
          aB[tN] = __builtin_amdgcn_mfma_f32_16x16x32_bf16(afB, bwh[tN][kb + 4], aB[tN], 0, 0, 0);
        }
#pragma unroll
        for (int tN = 0; tN < 4; tN++) {
          aA[tN] = __builtin_amdgcn_mfma_f32_16x16x32_bf16(afA, bwl[tN][kb], aA[tN], 0, 0, 0);
          aB[tN] = __builtin_amdgcn_mfma_f32_16x16x32_bf16(afB, bwl[tN][kb + 4], aB[tN], 0, 0, 0);
        }
      }

      // Epilogue, all lanes: quad q consumes n-tile q (C rows 4q,4q+1 ==
      // rows 0,1 bit-exactly). Static 4-way select, then same recombine
      // order as R13: (hi + lo) + c.
      {
        float sA0 = quad < 2 ? (quad == 0 ? aA[0][0] : aA[1][0]) : (quad == 2 ? aA[2][0] : aA[3][0]);
        float sA1 = quad < 2 ? (quad == 0 ? aA[0][1] : aA[1][1]) : (quad == 2 ? aA[2][1] : aA[3][1]);
        float sB0 = quad < 2 ? (quad == 0 ? aB[0][0] : aB[1][0]) : (quad == 2 ? aB[2][0] : aB[3][0]);
        float sB1 = quad < 2 ? (quad == 0 ? aB[0][1] : aB[1][1]) : (quad == 2 ? aB[2][1] : aB[3][1]);
        float hi_part = sA0 + sB0;
        float lo_part = sA1 + sB1;
        float x = (hi_part + lo_part) + cb[k];
        float y = tanh_fast(x);
        HiLo s = splitf(y);
        hw[cwl] = s.hi;           // row 0 = h_hi
        hw[HP_B + cwl] = s.lo;    // row 1 = h_lo
        *outp = y;                // fire-and-forget (vmcnt never drained)
      }
      outp += 256;

      // Prefetch c for step m+4 into the bank just consumed.
      if (m4 <= 1019 - k) {
        cb[k] = *ldp;
        ldp += 2048;
      }
      sync_lds_only();
    }
  }
}

extern "C" void kernel_launch(void* const* d_in, const int* in_sizes, int n_in,
                              void* d_out, int out_size, void* d_ws, size_t ws_size,
                              hipStream_t stream) {
  (void)in_sizes; (void)n_in; (void)out_size; (void)ws_size;
  const float* seq   = (const float*)d_in[0];  // (8,1024,256) f32
  const float* graph = (const float*)d_in[1];  // (8,1024,1024) f32
  const float* E     = (const float*)d_in[2];  // (256,256) f32
  const float* Wx    = (const float*)d_in[3];  // (256,256) f32
  const float* Wh    = (const float*)d_in[4];  // (256,256) f32
  const float* bias  = (const float*)d_in[5];  // (256,) f32
  float* out = (float*)d_out;                  // (8,1024,256) f32

  // workspace layout (bytes): ~26 MB total
  char* w = (char*)d_ws;
  float* rnorm  = (float*)(w + 0);          //  32 KB
  u16*   Eth    = (u16*)(w + 32768);        // 128 KB
  u16*   Etl    = (u16*)(w + 163840);
  u16*   Wxth   = (u16*)(w + 294912);
  u16*   Wxtl   = (u16*)(w + 425984);
  u16*   Whth   = (u16*)(w + 557056);
  u16*   Whtl   = (u16*)(w + 688128);
  u16*   betaTh = (u16*)(w + 819200);       // 4 MB [b][u][l]
  u16*   betaTl = (u16*)(w + 5013504);      // 4 MB
  float* agg    = (float*)(w + 9207808);    // 8 MB [b][m][u]
  float* Xpre   = (float*)(w + 17596416);   // 8 MB [m][b][u]

  transpose_split3<<<dim3(256, 3), 256, 0, stream>>>(E, Eth, Etl, Wx, Wxth, Wxtl, Wh, Whth, Whtl);
  rowsum_norm<<<2048, 256, 0, stream>>>(graph, rnorm);
  gemm_beta<<<dim3(128, 4), 256, 0, stream>>>(seq, Eth, Etl, rnorm, betaTh, betaTl);
  gemm_agg<<<dim3(16, 4, 8), 256, 0, stream>>>(graph, betaTh, betaTl, agg);
  gemm_xpre<<<dim3(128, 4), 256, 0, stream>>>(agg, Wxth, Wxtl, bias, Xpre);
  rnn_scan<<<dim3(8), 256, 0, stream>>>(Whth, Whtl, Xpre, out);
}

// Round 4
// 777.544 us; speedup vs baseline: 1.2510x; 1.2510x over previous
//
#include <hip/hip_runtime.h>
#include <hip/hip_bf16.h>

// GraphRNN, fp32 I/O (reference dtypes are float32).
// beta = (seq @ E) / rowsum(graph); agg = graph^T @ beta (per batch);
// Xpre = agg @ Wx + b; then 1024-step scan h = tanh(Xpre_m + h @ Wh).
// MFMA path: fp32 operands split into bf16 hi+lo (rel err ~2^-18).
//
// R15: back to R13's 8-wave scan (2 waves/SIMD is REQUIRED: R14's 1
// wave/SIMD exposed all wave-serial stalls -> 1907cy/step). Scan floor:
// 256 MFMAs/WG/step x ~19.4cy/SIMD-MFMA (m06-derived) = ~1242cy/SIMD,
// irreducible (N=256 x K=256 x Wh hi/lo; M-waste trades only against
// batches/CU; dropping Wh_lo fails precision: per-step err amplifies
// ~2^9 through the recurrence). R13 = 1590cy -> ~350cy of lockstep
// bubbles. R15 shaves the tail: (a) epilogue distributed quad0->tile0,
// quad1->tile1 (1 tanh chain/lane, was 2 serial on quad0; same recombine
// order -> bit-identical); (b) all 8 ds_reads hoisted to step top;
// (c) K0+K1 merged into one launch. Math bit-identical to R13.

typedef unsigned short u16;
typedef unsigned int u32;
typedef __bf16 bf16_t;
typedef __bf16 bf16x8 __attribute__((ext_vector_type(8)));
typedef float f32x4 __attribute__((ext_vector_type(4)));
typedef unsigned short u16x8 __attribute__((ext_vector_type(8)));
typedef unsigned short u16x4 __attribute__((ext_vector_type(4)));

#define LDS_P 72   // LDS pitch (u16) for 64-wide tiles (GEMM kernels)
#define HP_B  288  // h LDS row pitch (u16): row1 starts at dword 144 ->
                   // banks 16.. for row1 vs 0..15 for row0 chunks

struct HiLo { u16 hi, lo; };

__device__ __forceinline__ u16 f2bf(float f) {
  bf16_t h = (bf16_t)f;  // RNE
  return __builtin_bit_cast(u16, h);
}
__device__ __forceinline__ HiLo splitf(float v) {
  bf16_t h = (bf16_t)v;
  HiLo r;
  r.hi = __builtin_bit_cast(u16, h);
  r.lo = f2bf(v - (float)h);
  return r;
}
__device__ __forceinline__ float tanh_fast(float x) {
  float ax = fabsf(x);
  float e  = __expf(-2.0f * ax);
  float t  = __fdividef(1.0f - e, 1.0f + e);
  return copysignf(t, x);
}
// Barrier with LDS-only visibility (drains lgkmcnt, not vmcnt).
__device__ __forceinline__ void sync_lds_only() {
  __asm__ volatile("s_waitcnt lgkmcnt(0)\ns_barrier" ::: "memory");
}

// ---------------- K0+K1 fused: weight transpose/split + graph row-sums -----
// bid < 768: transpose+split E/Wx/Wh (mat = bid>>8, u = bid&255).
// bid >= 768: rnorm[b,l] = 1 / max(sum_m graph[b,l,m], 1e-7), 4 rows/block.
__global__ void prep_split_rowsum(const float* __restrict__ E, u16* __restrict__ Eth, u16* __restrict__ Etl,
                                  const float* __restrict__ Wx, u16* __restrict__ Wxth, u16* __restrict__ Wxtl,
                                  const float* __restrict__ Wh, u16* __restrict__ Whth, u16* __restrict__ Whtl,
                                  const float* __restrict__ graph, float* __restrict__ rnorm) {
  const int bid = blockIdx.x;
  if (bid < 768) {
    const int mat = bid >> 8, u = bid & 255, d = threadIdx.x;
    const float* s; u16 *dh, *dl;
    if (mat == 0)      { s = E;  dh = Eth;  dl = Etl; }
    else if (mat == 1) { s = Wx; dh = Wxth; dl = Wxtl; }
    else               { s = Wh; dh = Whth; dl = Whtl; }
    HiLo r = splitf(s[d * 256 + u]);
    dh[u * 256 + d] = r.hi;
    dl[u * 256 + d] = r.lo;
  } else {
    const int wave = threadIdx.x >> 6, lane = threadIdx.x & 63;
    const int row = (bid - 768) * 4 + wave;  // 0..8191
    const float* p = graph + (size_t)row * 1024 + lane * 16;
    float s = 0.f;
#pragma unroll
    for (int c = 0; c < 4; c++) {
      f32x4 v = *(const f32x4*)(p + c * 4);
#pragma unroll
      for (int j = 0; j < 4; j++) s += v[j];
    }
#pragma unroll
    for (int off = 32; off > 0; off >>= 1) s += __shfl_xor(s, off);
    if (lane == 0) rnorm[row] = 1.0f / fmaxf(s, 1e-7f);
  }
}

// ---------------- K2: betaT[b][u][l] hi/lo = (seq@E)[b,l,u] * rnorm[b,l] ----
__global__ __launch_bounds__(256, 2) void gemm_beta(const float* __restrict__ seq,
                                                    const u16* __restrict__ Eth,
                                                    const u16* __restrict__ Etl,
                                                    const float* __restrict__ rnorm,
                                                    u16* __restrict__ betaTh,
                                                    u16* __restrict__ betaTl) {
  __shared__ u16 Ah[64 * LDS_P], Al[64 * LDS_P];
  __shared__ u16 Bh[64 * LDS_P], Bl[64 * LDS_P];
  const int t = threadIdx.x;
  const int wave = t >> 6, lane = t & 63, quad = lane >> 4, l16 = lane & 15;
  const int r0 = blockIdx.x * 64, n0 = blockIdx.y * 64;
  f32x4 acc[4];
#pragma unroll
  for (int i = 0; i < 4; i++) acc[i] = (f32x4){0.f, 0.f, 0.f, 0.f};

  for (int kb = 0; kb < 256; kb += 64) {
#pragma unroll
    for (int cc = 0; cc < 4; cc++) {
      int c = t + cc * 256;
      int r = c >> 4, c4 = c & 15;
      f32x4 v = *(const f32x4*)(seq + (size_t)(r0 + r) * 256 + kb + c4 * 4);
      u16x4 hi, lo;
#pragma unroll
      for (int j = 0; j < 4; j++) {
        HiLo s = splitf(v[j]);
        hi[j] = s.hi; lo[j] = s.lo;
      }
      *(u16x4*)(Ah + r * LDS_P + c4 * 4) = hi;
      *(u16x4*)(Al + r * LDS_P + c4 * 4) = lo;
    }
#pragma unroll
    for (int cc = 0; cc < 2; cc++) {
      int c = t + cc * 256;
      int r = c >> 3, c8 = c & 7;
      *(u16x8*)(Bh + r * LDS_P + c8 * 8) =
          *(const u16x8*)(Eth + (size_t)(n0 + r) * 256 + kb + c8 * 8);
      *(u16x8*)(Bl + r * LDS_P + c8 * 8) =
          *(const u16x8*)(Etl + (size_t)(n0 + r) * 256 + kb + c8 * 8);
    }
    __syncthreads();
#pragma unroll
    for (int kk = 0; kk < 64; kk += 32) {
      bf16x8 ah = __builtin_bit_cast(bf16x8, *(const u16x8*)(Ah + (wave * 16 + l16) * LDS_P + kk + quad * 8));
      bf16x8 al = __builtin_bit_cast(bf16x8, *(const u16x8*)(Al + (wave * 16 + l16) * LDS_P + kk + quad * 8));
#pragma unroll
      for (int tN = 0; tN < 4; tN++) {
        bf16x8 bh = __builtin_bit_cast(bf16x8, *(const u16x8*)(Bh + (tN * 16 + l16) * LDS_P + kk + quad * 8));
        bf16x8 bl = __builtin_bit_cast(bf16x8, *(const u16x8*)(Bl + (tN * 16 + l16) * LDS_P + kk + quad * 8));
        acc[tN] = __builtin_amdgcn_mfma_f32_16x16x32_bf16(ah, bh, acc[tN], 0, 0, 0);
        acc[tN] = __builtin_amdgcn_mfma_f32_16x16x32_bf16(ah, bl, acc[tN], 0, 0, 0);
        acc[tN] = __builtin_amdgcn_mfma_f32_16x16x32_bf16(al, bh, acc[tN], 0, 0, 0);
      }
    }
    __syncthreads();
  }
  const int rbase = r0 + wave * 16 + quad * 4;  // b*1024 + l, 4 consecutive l
  float rn[4];
#pragma unroll
  for (int i = 0; i < 4; i++) rn[i] = rnorm[rbase + i];
  const int bI = rbase >> 10, lI = rbase & 1023;
#pragma unroll
  for (int tN = 0; tN < 4; tN++) {
    int u = n0 + tN * 16 + l16;
    u16x4 hv, lv;
#pragma unroll
    for (int i = 0; i < 4; i++) {
      HiLo s = splitf(acc[tN][i] * rn[i]);
      hv[i] = s.hi; lv[i] = s.lo;
    }
    size_t off = ((size_t)bI << 18) + (size_t)u * 1024 + lI;
    *(u16x4*)(betaTh + off) = hv;
    *(u16x4*)(betaTl + off) = lv;
  }
}

// ---------------- K3: agg[b][m][u] = sum_l graph[b][l][m] * beta[b][l][u] ---
__global__ __launch_bounds__(256, 2) void gemm_agg(const float* __restrict__ graph,
                                                   const u16* __restrict__ betaTh,
                                                   const u16* __restrict__ betaTl,
                                                   float* __restrict__ agg) {
  __shared__ u16 Ah[64 * LDS_P], Al[64 * LDS_P];
  __shared__ u16 Bh[64 * LDS_P], Bl[64 * LDS_P];
  const int t = threadIdx.x;
  const int wave = t >> 6, lane = t & 63, quad = lane >> 4, l16 = lane & 15;
  const int m0 = blockIdx.x * 64, n0 = blockIdx.y * 64, b = blockIdx.z;
  const float* g = graph + (size_t)b * (1024 * 1024);
  const size_t bt = (size_t)b << 18;
  f32x4 acc[4];
#pragma unroll
  for (int i = 0; i < 4; i++) acc[i] = (f32x4){0.f, 0.f, 0.f, 0.f};

  for (int kb = 0; kb < 1024; kb += 64) {
#pragma unroll
    for (int cc = 0; cc < 4; cc++) {
      int c = t + cc * 256;
      int r = c >> 4, c4 = c & 15;  // r = l_local, c4 = m-chunk of 4
      f32x4 v = *(const f32x4*)(g + (size_t)(kb + r) * 1024 + m0 + c4 * 4);
#pragma unroll
      for (int j = 0; j < 4; j++) {
        HiLo s = splitf(v[j]);
        Ah[(c4 * 4 + j) * LDS_P + r] = s.hi;  // A[m][l] = graph[l][m]
        Al[(c4 * 4 + j) * LDS_P + r] = s.lo;
      }
    }
#pragma unroll
    for (int cc = 0; cc < 2; cc++) {
      int c = t + cc * 256;
      int r = c >> 3, c8 = c & 7;
      *(u16x8*)(Bh + r * LDS_P + c8 * 8) =
          *(const u16x8*)(betaTh + bt + (size_t)(n0 + r) * 1024 + kb + c8 * 8);
      *(u16x8*)(Bl + r * LDS_P + c8 * 8) =
          *(const u16x8*)(betaTl + bt + (size_t)(n0 + r) * 1024 + kb + c8 * 8);
    }
    __syncthreads();
#pragma unroll
    for (int kk = 0; kk < 64; kk += 32) {
      bf16x8 ah = __builtin_bit_cast(bf16x8, *(const u16x8*)(Ah + (wave * 16 + l16) * LDS_P + kk + quad * 8));
      bf16x8 al = __builtin_bit_cast(bf16x8, *(const u16x8*)(Al + (wave * 16 + l16) * LDS_P + kk + quad * 8));
#pragma unroll
      for (int tN = 0; tN < 4; tN++) {
        bf16x8 bh = __builtin_bit_cast(bf16x8, *(const u16x8*)(Bh + (tN * 16 + l16) * LDS_P + kk + quad * 8));
        bf16x8 bl = __builtin_bit_cast(bf16x8, *(const u16x8*)(Bl + (tN * 16 + l16) * LDS_P + kk + quad * 8));
        acc[tN] = __builtin_amdgcn_mfma_f32_16x16x32_bf16(ah, bh, acc[tN], 0, 0, 0);
        acc[tN] = __builtin_amdgcn_mfma_f32_16x16x32_bf16(ah, bl, acc[tN], 0, 0, 0);
        acc[tN] = __builtin_amdgcn_mfma_f32_16x16x32_bf16(al, bh, acc[tN], 0, 0, 0);
      }
    }
    __syncthreads();
  }
  const int mbase = m0 + wave * 16 + quad * 4;
#pragma unroll
  for (int tN = 0; tN < 4; tN++) {
    int u = n0 + tN * 16 + l16;
#pragma unroll
    for (int i = 0; i < 4; i++)
      agg[((size_t)b * 1024 + mbase + i) * 256 + u] = acc[tN][i];
  }
}

// ---------------- K4: Xpre[m][b][u] = (agg @ Wx)[b,m,u] + bias[u] (fp32) ----
__global__ __launch_bounds__(256, 2) void gemm_xpre(const float* __restrict__ agg,
                                                    const u16* __restrict__ Wxth,
                                                    const u16* __restrict__ Wxtl,
                                                    const float* __restrict__ bias,
                                                    float* __restrict__ Xpre) {
  __shared__ u16 Ah[64 * LDS_P], Al[64 * LDS_P];
  __shared__ u16 Bh[64 * LDS_P], Bl[64 * LDS_P];
  const int t = threadIdx.x;
  const int wave = t >> 6, lane = t & 63, quad = lane >> 4, l16 = lane & 15;
  const int r0 = blockIdx.x * 64, n0 = blockIdx.y * 64;
  f32x4 acc[4];
#pragma unroll
  for (int i = 0; i < 4; i++) acc[i] = (f32x4){0.f, 0.f, 0.f, 0.f};

  for (int kb = 0; kb < 256; kb += 64) {
#pragma unroll
    for (int cc = 0; cc < 4; cc++) {
      int c = t + cc * 256;
      int r = c >> 4, c4 = c & 15;
      f32x4 v = *(const f32x4*)(agg + (size_t)(r0 + r) * 256 + kb + c4 * 4);
      u16x4 hi, lo;
#pragma unroll
      for (int j = 0; j < 4; j++) {
        HiLo s = splitf(v[j]);
        hi[j] = s.hi; lo[j] = s.lo;
      }
      *(u16x4*)(Ah + r * LDS_P + c4 * 4) = hi;
      *(u16x4*)(Al + r * LDS_P + c4 * 4) = lo;
    }
#pragma unroll
    for (int cc = 0; cc < 2; cc++) {
      int c = t + cc * 256;
      int r = c >> 3, c8 = c & 7;
      *(u16x8*)(Bh + r * LDS_P + c8 * 8) =
          *(const u16x8*)(Wxth + (size_t)(n0 + r) * 256 + kb + c8 * 8);
      *(u16x8*)(Bl + r * LDS_P + c8 * 8) =
          *(const u16x8*)(Wxtl + (size_t)(n0 + r) * 256 + kb + c8 * 8);
    }
    __syncthreads();
#pragma unroll
    for (int kk = 0; kk < 64; kk += 32) {
      bf16x8 ah = __builtin_bit_cast(bf16x8, *(const u16x8*)(Ah + (wave * 16 + l16) * LDS_P + kk + quad * 8));
      bf16x8 al = __builtin_bit_cast(bf16x8, *(const u16x8*)(Al + (wave * 16 + l16) * LDS_P + kk + quad * 8));
#pragma unroll
      for (int tN = 0; tN < 4; tN++) {
        bf16x8 bh = __builtin_bit_cast(bf16x8, *(const u16x8*)(Bh + (tN * 16 + l16) * LDS_P + kk + quad * 8));
        bf16x8 bl = __builtin_bit_cast(bf16x8, *(const u16x8*)(Bl + (tN * 16 + l16) * LDS_P + kk + quad * 8));
        acc[tN] = __builtin_amdgcn_mfma_f32_16x16x32_bf16(ah, bh, acc[tN], 0, 0, 0);
        acc[tN] = __builtin_amdgcn_mfma_f32_16x16x32_bf16(ah, bl, acc[tN], 0, 0, 0);
        acc[tN] = __builtin_amdgcn_mfma_f32_16x16x32_bf16(al, bh, acc[tN], 0, 0, 0);
      }
    }
    __syncthreads();
  }
  const int rbase = r0 + wave * 16 + quad * 4;  // b*1024 + m
  const int bI = rbase >> 10;
#pragma unroll
  for (int tN = 0; tN < 4; tN++) {
    int u = n0 + tN * 16 + l16;
    float bu = bias[u];
#pragma unroll
    for (int i = 0; i < 4; i++) {
      int mI = (rbase + i) & 1023;
      Xpre[((size_t)mI * 8 + bI) * 256 + u] = acc[tN][i] + bu;
    }
  }
}

// ---------------- K5: sequential scan, 8 WGs (1 batch each), 8 waves --------
// Wave w owns output cols [w*32, w*32+32) = 2 n-tiles. A-tile: 2 rows
// (h_hi, h_lo), read row clamped to l16&1 -> broadcast, conflict-free.
// All C rows are bit-exact duplicates of rows 0/1, so quads 0 and 1 both
// hold valid (hi,lo) in C regs [0],[1] of their accumulators: quad0
// consumes n-tile 0, quad1 n-tile 1 -> 1 tanh chain/lane (was 2 serial).
// All 8 ds_reads hoisted to step top. Double-buffered h, lookahead-4
// c-banks, running pointers, in-step out-stores. Bit-identical math:
// same per-accumulator MFMA order, same recombine order as R13.
__global__ __launch_bounds__(512, 2) void rnn_scan(const u16* __restrict__ Whth,
                                                   const u16* __restrict__ Whtl,
                                                   const float* __restrict__ Xpre,
                                                   float* __restrict__ out) {
  __shared__ u16 h2[2][2 * HP_B];
  const int b = blockIdx.x;
  const int t = threadIdx.x;
  const int w = t >> 6, lane = t & 63, quad = lane >> 4, l16 = lane & 15;
  const int colbase = w * 32;
  const bool epi = (quad < 2);           // quad0 -> tile0, quad1 -> tile1
  const int col_e = colbase + quad * 16 + l16;  // valid for epi lanes

  // Preload Wh hi+lo fragments: 2 n-tiles x 8 k-blocks, hi+lo
  bf16x8 bwh[2][8], bwl[2][8];
#pragma unroll
  for (int tN = 0; tN < 2; tN++) {
    const u16* wph = Whth + (size_t)(colbase + tN * 16 + l16) * 256 + quad * 8;
    const u16* wpl = Whtl + (size_t)(colbase + tN * 16 + l16) * 256 + quad * 8;
#pragma unroll
    for (int kb = 0; kb < 8; kb++) {
      bwh[tN][kb] = __builtin_bit_cast(bf16x8, *(const u16x8*)(wph + kb * 32));
      bwl[tN][kb] = __builtin_bit_cast(bf16x8, *(const u16x8*)(wpl + kb * 32));
    }
  }
  for (int i = t; i < 2 * 2 * HP_B; i += 512) ((u16*)h2)[i] = 0;

  // c banks 0..3: additive input for steps m4+0..m4+3 (epi lanes only).
  float cb[4];
  if (epi) {
#pragma unroll
    for (int k = 0; k < 4; k++) cb[k] = Xpre[(size_t)k * 2048 + b * 256 + col_e];
  }
  // Running pointers (advance by constants; no per-step re-derivation).
  const float* ldp = Xpre + 4 * 2048 + b * 256 + col_e;
  float* outp = out + (size_t)b * 262144 + col_e;
  // Hoisted LDS bases. Read base: row clamped to l16&1 (broadcast dup rows).
  const u16* rb0 = &h2[0][(l16 & 1) * HP_B + quad * 8];
  const u16* rb1 = &h2[1][(l16 & 1) * HP_B + quad * 8];
  u16* wb0 = &h2[0][0];
  u16* wb1 = &h2[1][0];
  __syncthreads();

  for (int m4 = 0; m4 < 1024; m4 += 4) {
#pragma unroll
    for (int k = 0; k < 4; k++) {
      const int p = k & 1;                       // compile-time in unrolled body
      const u16* rb = p ? rb1 : rb0;
      u16* hw = p ? wb0 : wb1;                   // write the other buffer

      // Hoist all 8 A-fragment reads (one lgkmcnt ramp, MFMAs pipeline).
      bf16x8 af[8];
#pragma unroll
      for (int kb = 0; kb < 8; kb++)
        af[kb] = __builtin_bit_cast(bf16x8, *(const u16x8*)(rb + kb * 32));

      f32x4 a0a = {0.f,0.f,0.f,0.f}, a0b = {0.f,0.f,0.f,0.f};
      f32x4 a1a = {0.f,0.f,0.f,0.f}, a1b = {0.f,0.f,0.f,0.f};
#pragma unroll
      for (int kb = 0; kb < 4; kb++) {
        a0a = __builtin_amdgcn_mfma_f32_16x16x32_bf16(af[kb], bwh[0][kb], a0a, 0, 0, 0);
        a1a = __builtin_amdgcn_mfma_f32_16x16x32_bf16(af[kb], bwh[1][kb], a1a, 0, 0, 0);
        a0b = __builtin_amdgcn_mfma_f32_16x16x32_bf16(af[kb + 4], bwh[0][kb + 4], a0b, 0, 0, 0);
        a1b = __builtin_amdgcn_mfma_f32_16x16x32_bf16(af[kb + 4], bwh[1][kb + 4], a1b, 0, 0, 0);
        a0a = __builtin_amdgcn_mfma_f32_16x16x32_bf16(af[kb], bwl[0][kb], a0a, 0, 0, 0);
        a1a = __builtin_amdgcn_mfma_f32_16x16x32_bf16(af[kb], bwl[1][kb], a1a, 0, 0, 0);
        a0b = __builtin_amdgcn_mfma_f32_16x16x32_bf16(af[kb + 4], bwl[0][kb + 4], a0b, 0, 0, 0);
        a1b = __builtin_amdgcn_mfma_f32_16x16x32_bf16(af[kb + 4], bwl[1][kb + 4], a1b, 0, 0, 0);
      }

      // Epilogue distributed: quad0 uses (a0a,a0b), quad1 uses (a1a,a1b).
      // Same recombine order as R13: (hi_part + lo_part) + c.
      if (epi) {
        float sA0 = quad ? a1a[0] : a0a[0];
        float sA1 = quad ? a1a[1] : a0a[1];
        float sB0 = quad ? a1b[0] : a0b[0];
        float sB1 = quad ? a1b[1] : a0b[1];
        float hi_part = sA0 + sB0;
        float lo_part = sA1 + sB1;
        float x = (hi_part + lo_part) + cb[k];
        float y = tanh_fast(x);
        HiLo s = splitf(y);
        hw[col_e] = s.hi;           // row 0 = h_hi
        hw[HP_B + col_e] = s.lo;    // row 1 = h_lo
        *outp = y;                  // fire-and-forget (vmcnt never drained)
        // Prefetch c for step m+4 into the bank just consumed.
        if (m4 <= 1019 - k) {
          cb[k] = *ldp;
          ldp += 2048;
        }
      }
      outp += 256;
      sync_lds_only();
    }
  }
}

extern "C" void kernel_launch(void* const* d_in, const int* in_sizes, int n_in,
                              void* d_out, int out_size, void* d_ws, size_t ws_size,
                              hipStream_t stream) {
  (void)in_sizes; (void)n_in; (void)out_size; (void)ws_size;
  const float* seq   = (const float*)d_in[0];  // (8,1024,256) f32
  const float* graph = (const float*)d_in[1];  // (8,1024,1024) f32
  const float* E     = (const float*)d_in[2];  // (256,256) f32
  const float* Wx    = (const float*)d_in[3];  // (256,256) f32
  const float* Wh    = (const float*)d_in[4];  // (256,256) f32
  const float* bias  = (const float*)d_in[5];  // (256,) f32
  float* out = (float*)d_out;                  // (8,1024,256) f32

  // workspace layout (bytes): ~26 MB total
  char* w = (char*)d_ws;
  float* rnorm  = (float*)(w + 0);          //  32 KB
  u16*   Eth    = (u16*)(w + 32768);        // 128 KB
  u16*   Etl    = (u16*)(w + 163840);
  u16*   Wxth   = (u16*)(w + 294912);
  u16*   Wxtl   = (u16*)(w + 425984);
  u16*   Whth   = (u16*)(w + 557056);
  u16*   Whtl   = (u16*)(w + 688128);
  u16*   betaTh = (u16*)(w + 819200);       // 4 MB [b][u][l]
  u16*   betaTl = (u16*)(w + 5013504);      // 4 MB
  float* agg    = (float*)(w + 9207808);    // 8 MB [b][m][u]
  float* Xpre   = (float*)(w + 17596416);   // 8 MB [m][b][u]

  prep_split_rowsum<<<2816, 256, 0, stream>>>(E, Eth, Etl, Wx, Wxth, Wxtl, Wh, Whth, Whtl, graph, rnorm);
  gemm_beta<<<dim3(128, 4), 256, 0, stream>>>(seq, Eth, Etl, rnorm, betaTh, betaTl);
  gemm_agg<<<dim3(16, 4, 8), 256, 0, stream>>>(graph, betaTh, betaTl, agg);
  gemm_xpre<<<dim3(128, 4), 256, 0, stream>>>(agg, Wxth, Wxtl, bias, Xpre);
  rnn_scan<<<dim3(8), 512, 0, stream>>>(Whth, Whtl, Xpre, out);
}